// Round 4
// baseline (94.267 us; speedup 1.0000x reference)
//
#include <hip/hip_runtime.h>
#include <math.h>

#define NB 16      // batch
#define NC 80      // classes
#define HH 128
#define WW 128
#define HW (HH*WW)
#define HW4 (HW/4)
#define NPIX (NB*HH*WW)   // 262144
#define NM 32      // boxes per batch
#define IMG 512.0f
#define G8 8               // class groups
#define NCL (NC/G8)        // 10 classes per group
#define MAIN_BLOCKS (NB*16*G8)   // 2048

// output layout (float offsets)
#define OFF_VALUES 0
#define OFF_IDXS   262144
#define OFF_BBOX   524288
#define OFF_KEEP   1572864
#define OFF_PFL    1835008
#define OFF_SZL    1835009
#define OFF_OSL    1835010
#define OFF_GTHM   1835011   // ≡3 mod 4 floats -> gt_hm not 16B aligned; scalar stores

// ws layout (bytes)
#define WS_BP    0          // 512 * 16 = 8192
#define WS_CSRS  8192       // 16*81*4 = 5184
#define WS_CSRO  13376      // 512*4 = 2048
#define WS_FPART 15424      // 2048*4 = 8192 -> ends 23616
#define WS_PACK  24576      // NPIX*8 = 2 MB

struct BoxParam { float ci0, ci1, inv2sig; int cls; };

__device__ __forceinline__ float smooth_l1(float p, float g) {
    float d = fabsf(p - g);
    return (d < 1.0f) ? 0.5f * d * d : d - 0.5f;
}
__device__ __forceinline__ float fmax3(float a, float b, float c) {
    return fmaxf(fmaxf(a, b), c);
}

// ---------------- kernel 1: zero packed buffer + box params + CSR ----------------
// grid 1024 x 256: every thread zeroes one u64; block 0 also does setup.
__global__ void zero_setup_kernel(const float* __restrict__ gtb, const int* __restrict__ gtc,
                                  BoxParam* __restrict__ bp, int* __restrict__ csr_start,
                                  int* __restrict__ csr_order,
                                  unsigned long long* __restrict__ packed) {
    int gt = blockIdx.x * 256 + threadIdx.x;
    packed[gt] = 0ULL;
    if (blockIdx.x != 0) return;
    int t0 = threadIdx.x;
    for (int t = t0; t < NB * NM; t += 256) {
        const float* g = gtb + t * 4;
        float x1 = g[0], y1 = g[1], x2 = g[2], y2 = g[3];
        float cx = (x1 + x2) * 0.5f, cy = (y1 + y2) * 0.5f;
        float c0 = floorf(cx * 0.25f);
        float c1 = floorf(cy * 0.25f);
        float w = x2 - x1, h = y2 - y1;
        float sigma = fmaxf(w, h) * 0.25f;     // sizes.max(-1)/DS
        BoxParam p;
        p.ci0 = c0; p.ci1 = c1;
        p.inv2sig = 1.0f / (2.0f * sigma);
        p.cls = gtc[t];
        bp[t] = p;
    }
    __syncthreads();
    if (t0 < NB) {
        int b = t0;
        int base = b * NM;
        int cnt[NC + 1];
        for (int c = 0; c <= NC; ++c) cnt[c] = 0;
        for (int m = 0; m < NM; ++m) cnt[bp[base + m].cls + 1]++;
        for (int c = 0; c < NC; ++c) cnt[c + 1] += cnt[c];
        int* st = csr_start + b * (NC + 1);
        for (int c = 0; c <= NC; ++c) st[c] = cnt[c];
        int pos[NC];
        for (int c = 0; c < NC; ++c) pos[c] = cnt[c];
        for (int m = 0; m < NM; ++m) {
            int c = bp[base + m].cls;
            csr_order[base + pos[c]++] = m;
        }
    }
}

// ---------------- kernel 2: fused NMS + gt_hm + focal, 4 px/lane, G=8 groups ----------------
// tile = 8 rows x 128 cols, 256 threads, lane owns a float4. 2048 blocks = 32 waves/CU.
__launch_bounds__(256, 8)
__global__ void main_kernel(const float* __restrict__ hm,
                            const BoxParam* __restrict__ bp,
                            const int* __restrict__ csr_start,
                            const int* __restrict__ csr_order,
                            unsigned long long* __restrict__ packed,
                            float* __restrict__ fpart,
                            float* __restrict__ out) {
    int blk = blockIdx.x;
    int g = blk & (G8 - 1);
    int t2 = blk >> 3;             // 0 .. NB*16-1
    int b = t2 >> 4;
    int i0 = (t2 & 15) << 3;       // 8 rows / tile
    int tid = threadIdx.x;
    int row = tid >> 5;            // 0..7
    int jb  = (tid & 31) << 2;     // col base, multiple of 4
    int i = i0 + row;
    int c0 = g * NCL;

    __shared__ int   s_start[NC + 1];
    __shared__ float s_box[NM][3];
    __shared__ int   s_ord[NM];
    for (int k = tid; k < NC + 1; k += 256) s_start[k] = csr_start[b * (NC + 1) + k];
    if (tid < NM) {
        BoxParam p = bp[b * NM + tid];
        s_box[tid][0] = p.ci0; s_box[tid][1] = p.ci1; s_box[tid][2] = p.inv2sig;
        s_ord[tid] = csr_order[b * NM + tid];
    }
    __syncthreads();

    const float fi = (float)i, fjb = (float)jb;
    int iu  = (i > 0) ? i - 1 : 0;
    int idn = (i < HH - 1) ? i + 1 : HH - 1;
    size_t base = ((size_t)b * NC + c0) * HW;

    const float4* pC = (const float4*)(hm + base + i   * WW + jb);
    const float4* pU = (const float4*)(hm + base + iu  * WW + jb);
    const float4* pD = (const float4*)(hm + base + idn * WW + jb);
    float* gp = out + OFF_GTHM + base + i * WW + jb;   // 4B-aligned only

    int lane31 = tid & 31;
    bool clampL = (lane31 == 0);
    bool clampR = (lane31 == 31);

    float bestv[4] = {-1.f, -1.f, -1.f, -1.f};
    int   bestc[4] = {0, 0, 0, 0};
    float facc = 0.0f;

    auto process = [&](float4 cC, float4 cU, float4 cD, int c, float* gpc) {
        float h[4] = {cC.x, cC.y, cC.z, cC.w};
        float vm[4];
        vm[0] = fmax3(cU.x, h[0], cD.x);
        vm[1] = fmax3(cU.y, h[1], cD.y);
        vm[2] = fmax3(cU.z, h[2], cD.z);
        vm[3] = fmax3(cU.w, h[3], cD.w);
        float left  = __shfl_up(vm[3], 1);
        float right = __shfl_down(vm[0], 1);
        if (clampL) left  = vm[0];
        if (clampR) right = vm[3];
        float mx[4];
        mx[0] = fmax3(left,  vm[0], vm[1]);
        mx[1] = fmax3(vm[0], vm[1], vm[2]);
        mx[2] = fmax3(vm[1], vm[2], vm[3]);
        mx[3] = fmax3(vm[2], vm[3], right);
        #pragma unroll
        for (int k = 0; k < 4; ++k) {
            float p = (h[k] >= mx[k]) ? h[k] : 0.0f;
            if (p > bestv[k]) { bestv[k] = p; bestc[k] = c; }
        }

        int s0 = s_start[c], s1 = s_start[c + 1];
        if (s0 == s1) {
            __builtin_nontemporal_store(0.0f, gpc + 0);
            __builtin_nontemporal_store(0.0f, gpc + 1);
            __builtin_nontemporal_store(0.0f, gpc + 2);
            __builtin_nontemporal_store(0.0f, gpc + 3);
            #pragma unroll
            for (int k = 0; k < 4; ++k)
                facc += h[k] * h[k] * __logf(1.0f - h[k]);
        } else {
            float gv[4] = {0.f, 0.f, 0.f, 0.f};
            for (int kk = s0; kk < s1; ++kk) {
                int m = s_ord[kk];
                float d0 = fi - s_box[m][0];
                float nis = -s_box[m][2];
                float dj = fjb - s_box[m][1];
                float e = d0 * d0;
                #pragma unroll
                for (int k = 0; k < 4; ++k) {
                    float d1 = dj + (float)k;
                    gv[k] = fmaxf(gv[k], __expf((e + d1 * d1) * nis));
                }
            }
            __builtin_nontemporal_store(gv[0], gpc + 0);
            __builtin_nontemporal_store(gv[1], gpc + 1);
            __builtin_nontemporal_store(gv[2], gpc + 2);
            __builtin_nontemporal_store(gv[3], gpc + 3);
            #pragma unroll
            for (int k = 0; k < 4; ++k) {
                float hk = h[k], ohk = 1.0f - hk;
                float gk = gv[k], omk = 1.0f - gk;
                float om2 = omk * omk, g2 = gk * gk;
                facc += (om2 * om2) * hk * hk * __logf(ohk)
                      + (g2 * g2) * ohk * ohk * __logf(hk);
            }
        }
    };

    float4 cC = *pC, cU = *pU, cD = *pD;
    for (int cc = 0; cc < NCL - 1; ++cc) {
        float4 nC = pC[HW4], nU = pU[HW4], nD = pD[HW4];   // prefetch next class
        process(cC, cU, cD, c0 + cc, gp);
        pC += HW4; pU += HW4; pD += HW4; gp += HW;
        cC = nC; cU = nU; cD = nD;
    }
    process(cC, cU, cD, c0 + NCL - 1, gp);

    // cross-group argmax via packed atomicMax:
    // high32 = float bits of best (>=0 so monotone), low32 = NC-1-class so ties pick smallest class
    int pixbase = (b * HH + i) * WW + jb;
    #pragma unroll
    for (int k = 0; k < 4; ++k) {
        unsigned long long pk =
            ((unsigned long long)__float_as_uint(bestv[k]) << 32) |
            (unsigned int)(NC - 1 - bestc[k]);
        atomicMax(packed + pixbase + k, pk);
    }

    #pragma unroll
    for (int off = 32; off > 0; off >>= 1) facc += __shfl_down(facc, off);
    __shared__ float s_red[4];
    if ((tid & 63) == 0) s_red[tid >> 6] = facc;
    __syncthreads();
    if (tid == 0)
        fpart[blk] = s_red[0] + s_red[1] + s_red[2] + s_red[3];
}

// ---------------- kernel 3: unpack + bbox decode, 4 px/thread ----------------
__global__ void combine_kernel(const unsigned long long* __restrict__ packed,
                               const float* __restrict__ sz, const float* __restrict__ osr,
                               float* __restrict__ out) {
    int p4 = blockIdx.x * 256 + threadIdx.x;
    int px = p4 << 2;
    ulonglong2 pa = *(const ulonglong2*)(packed + px);
    ulonglong2 pb = *(const ulonglong2*)(packed + px + 2);
    unsigned long long pk[4] = {pa.x, pa.y, pb.x, pb.y};
    float bv[4]; int bi[4];
    #pragma unroll
    for (int k = 0; k < 4; ++k) {
        bv[k] = __uint_as_float((unsigned int)(pk[k] >> 32));
        bi[k] = NC - 1 - (int)(unsigned int)(pk[k] & 0xffffffffu);
    }
    float4 vals = {bv[0], bv[1], bv[2], bv[3]};
    float4 idxf = {(float)bi[0], (float)bi[1], (float)bi[2], (float)bi[3]};
    float4 keep = {bv[0] > 0.f ? 1.f : 0.f, bv[1] > 0.f ? 1.f : 0.f,
                   bv[2] > 0.f ? 1.f : 0.f, bv[3] > 0.f ? 1.f : 0.f};
    *(float4*)(out + OFF_VALUES + px) = vals;
    *(float4*)(out + OFF_IDXS + px)   = idxf;
    *(float4*)(out + OFF_KEEP + px)   = keep;

    int b = px >> 14, ij = px & 16383;
    float fi = (float)(ij >> 7), fjb = (float)(ij & 127);
    const float* szb = sz  + (size_t)b * 2 * HW;
    const float* osb = osr + (size_t)b * 2 * HW;
    float4 s0v = *(const float4*)(szb + ij);
    float4 s1v = *(const float4*)(szb + HW + ij);
    float4 o0v = *(const float4*)(osb + ij);
    float4 o1v = *(const float4*)(osb + HW + ij);
    float s0a[4] = {s0v.x, s0v.y, s0v.z, s0v.w};
    float s1a[4] = {s1v.x, s1v.y, s1v.z, s1v.w};
    float o0a[4] = {o0v.x, o0v.y, o0v.z, o0v.w};
    float o1a[4] = {o1v.x, o1v.y, o1v.z, o1v.w};
    #pragma unroll
    for (int k = 0; k < 4; ++k) {
        float cx = fi * 4.0f + o0a[k];
        float cy = (fjb + (float)k) * 4.0f + o1a[k];
        float4 bb;
        bb.x = fminf(fmaxf(cx - s0a[k] * 0.5f, 0.0f), IMG);
        bb.y = fminf(fmaxf(cy - s1a[k] * 0.5f, 0.0f), IMG);
        bb.z = fminf(fmaxf(cx + s0a[k] * 0.5f, 0.0f), IMG);
        bb.w = fminf(fmaxf(cy + s1a[k] * 0.5f, 0.0f), IMG);
        reinterpret_cast<float4*>(out + OFF_BBOX)[px + k] = bb;
    }
}

// ---------------- kernel 4: size/offset losses + focal partial reduction ----------------
__global__ void loss_kernel(const float* __restrict__ gtb, const float* __restrict__ sz,
                            const float* __restrict__ osr, const float* __restrict__ fpart,
                            float* __restrict__ out) {
    int t = threadIdx.x;
    int b = t >> 5, m = t & 31;
    __shared__ int s_ci[NB * NM];
    const float* g = gtb + t * 4;
    float x1 = g[0], y1 = g[1], x2 = g[2], y2 = g[3];
    float cx = (x1 + x2) * 0.5f, cy = (y1 + y2) * 0.5f;
    float c0f = floorf(cx * 0.25f), c1f = floorf(cy * 0.25f);
    int ci0 = (int)c0f, ci1 = (int)c1f;
    s_ci[t] = ci0 * WW + ci1;
    __syncthreads();

    bool winner = true;
    int mycell = s_ci[t];
    for (int m2 = m + 1; m2 < NM; ++m2)
        if (s_ci[b * NM + m2] == mycell) { winner = false; break; }

    float nloc = 0.0f, szs = 0.0f, oss = 0.0f;
    if (winner) {
        nloc = 1.0f;
        float w = x2 - x1, h = y2 - y1;
        float offx = cx * 0.25f - c0f, offy = cy * 0.25f - c1f;
        size_t pb = (size_t)b * 2 * HW + (size_t)ci0 * WW + ci1;
        float ps0 = sz[pb], ps1 = sz[pb + HW];
        float po0 = osr[pb], po1 = osr[pb + HW];
        szs = smooth_l1(ps0, w) + smooth_l1(ps1, h);
        oss = smooth_l1(po0, offx) + smooth_l1(po1, offy);
    }

    // focal partials: 2048 entries, 4 per thread
    float fsum = fpart[t] + fpart[t + 512] + fpart[t + 1024] + fpart[t + 1536];

    #pragma unroll
    for (int off = 32; off > 0; off >>= 1) {
        nloc += __shfl_down(nloc, off);
        szs  += __shfl_down(szs, off);
        oss  += __shfl_down(oss, off);
        fsum += __shfl_down(fsum, off);
    }
    __shared__ float red[8][4];
    int wid = t >> 6;
    if ((t & 63) == 0) { red[wid][0] = nloc; red[wid][1] = szs; red[wid][2] = oss; red[wid][3] = fsum; }
    __syncthreads();
    if (t == 0) {
        float n = 0.0f, ss = 0.0f, os_ = 0.0f, ft = 0.0f;
        for (int w2 = 0; w2 < 8; ++w2) { n += red[w2][0]; ss += red[w2][1]; os_ += red[w2][2]; ft += red[w2][3]; }
        out[OFF_SZL] = ss / (2.0f * n) / n;
        out[OFF_OSL] = os_ / (2.0f * n) / n;
        out[OFF_PFL] = -ft;
    }
}

extern "C" void kernel_launch(void* const* d_in, const int* in_sizes, int n_in,
                              void* d_out, int out_size, void* d_ws, size_t ws_size,
                              hipStream_t stream) {
    const float* hm  = (const float*)d_in[0];
    const float* sz  = (const float*)d_in[1];
    const float* osr = (const float*)d_in[2];
    const float* gtb = (const float*)d_in[3];
    const int*   gtc = (const int*)d_in[4];
    float* out = (float*)d_out;

    BoxParam* bp   = (BoxParam*)((char*)d_ws + WS_BP);
    int* csr_start = (int*)((char*)d_ws + WS_CSRS);
    int* csr_order = (int*)((char*)d_ws + WS_CSRO);
    float* fpart   = (float*)((char*)d_ws + WS_FPART);
    unsigned long long* packed = (unsigned long long*)((char*)d_ws + WS_PACK);

    zero_setup_kernel<<<NPIX / 256, 256, 0, stream>>>(gtb, gtc, bp, csr_start, csr_order, packed);
    main_kernel<<<MAIN_BLOCKS, 256, 0, stream>>>(hm, bp, csr_start, csr_order, packed, fpart, out);
    combine_kernel<<<NPIX / 4 / 256, 256, 0, stream>>>(packed, sz, osr, out);
    loss_kernel<<<1, 512, 0, stream>>>(gtb, sz, osr, fpart, out);
}

// Round 5
// 76.088 us; speedup vs baseline: 1.2389x; 1.2389x over previous
//
#include <hip/hip_runtime.h>
#include <math.h>

#define NB 16      // batch
#define NC 80      // classes
#define HH 128
#define WW 128
#define HW (HH*WW)
#define HW4 (HW/4)
#define NPIX (NB*HH*WW)   // 262144
#define NM 32      // boxes per batch
#define IMG 512.0f
#define NW 8               // waves per block = class groups
#define NCL (NC/NW)        // 10 classes per wave
#define MAIN_BLOCKS (NB*64)  // 1024 blocks, 2 rows each

// output layout (float offsets)
#define OFF_VALUES 0
#define OFF_IDXS   262144
#define OFF_BBOX   524288
#define OFF_KEEP   1572864
#define OFF_PFL    1835008
#define OFF_SZL    1835009
#define OFF_OSL    1835010
#define OFF_GTHM   1835011   // ≡3 mod 4 floats -> gt_hm not 16B aligned; scalar stores

// ws layout (bytes)
#define WS_BP    0          // 512*16 = 8192
#define WS_CSRS  8192       // 16*81*4 = 5184
#define WS_CSRO  13376      // 512*4 = 2048
#define WS_FPART 15424      // 1024*4 = 4096 -> ends 19520

struct BoxParam { float ci0, ci1, inv2sig; int cls; };

__device__ __forceinline__ float smooth_l1(float p, float g) {
    float d = fabsf(p - g);
    return (d < 1.0f) ? 0.5f * d * d : d - 0.5f;
}
__device__ __forceinline__ float fmax3(float a, float b, float c) {
    return fmaxf(fmaxf(a, b), c);
}

// ---------------- kernel 1: box params + per-batch class CSR ----------------
__global__ void setup_kernel(const float* __restrict__ gtb, const int* __restrict__ gtc,
                             BoxParam* __restrict__ bp, int* __restrict__ csr_start,
                             int* __restrict__ csr_order) {
    int t = threadIdx.x;  // blockDim = 512
    if (t < NB * NM) {
        const float* g = gtb + t * 4;
        float x1 = g[0], y1 = g[1], x2 = g[2], y2 = g[3];
        float cx = (x1 + x2) * 0.5f, cy = (y1 + y2) * 0.5f;
        float c0 = floorf(cx * 0.25f);
        float c1 = floorf(cy * 0.25f);
        float w = x2 - x1, h = y2 - y1;
        float sigma = fmaxf(w, h) * 0.25f;     // sizes.max(-1)/DS
        BoxParam p;
        p.ci0 = c0; p.ci1 = c1;
        p.inv2sig = 1.0f / (2.0f * sigma);
        p.cls = gtc[t];
        bp[t] = p;
    }
    __syncthreads();
    if (t < NB) {
        int b = t;
        int base = b * NM;
        int cnt[NC + 1];
        for (int c = 0; c <= NC; ++c) cnt[c] = 0;
        for (int m = 0; m < NM; ++m) cnt[bp[base + m].cls + 1]++;
        for (int c = 0; c < NC; ++c) cnt[c + 1] += cnt[c];
        int* st = csr_start + b * (NC + 1);
        for (int c = 0; c <= NC; ++c) st[c] = cnt[c];
        int pos[NC];
        for (int c = 0; c < NC; ++c) pos[c] = cnt[c];
        for (int m = 0; m < NM; ++m) {
            int c = bp[base + m].cls;
            csr_order[base + pos[c]++] = m;
        }
    }
}

// ---------------- kernel 2: one-stop NMS + gt_hm + focal + argmax + bbox ----------------
// Block = 512 threads = 8 waves. Tile = 2 rows x 128 cols (256 px).
// Each wave handles one 10-class group over the tile; 4 px/lane (1 row x 4 cols).
// Cross-group argmax via LDS table, then threads 0-255 write all per-pixel outputs.
__launch_bounds__(512, 8)
__global__ void main_kernel(const float* __restrict__ hm,
                            const float* __restrict__ sz,
                            const float* __restrict__ osr,
                            const BoxParam* __restrict__ bp,
                            const int* __restrict__ csr_start,
                            const int* __restrict__ csr_order,
                            float* __restrict__ fpart,
                            float* __restrict__ out) {
    int blk = blockIdx.x;
    int b = blk >> 6;
    int i0 = (blk & 63) << 1;        // 2 rows per tile
    int tid = threadIdx.x;
    int wid = tid >> 6;              // wave id = class group
    int lane = tid & 63;
    int lane31 = lane & 31;
    int r = lane >> 5;               // 0/1: row within tile
    int i = i0 + r;
    int jb = lane31 << 2;            // col base
    int c0 = wid * NCL;

    __shared__ int   s_start[NC + 1];
    __shared__ float s_box[NM][3];
    __shared__ int   s_ord[NM];
    __shared__ float s_val[NW][256];
    __shared__ unsigned char s_cls[NW][256];
    __shared__ float s_red[NW];

    for (int k = tid; k < NC + 1; k += 512) s_start[k] = csr_start[b * (NC + 1) + k];
    if (tid < NM) {
        BoxParam p = bp[b * NM + tid];
        s_box[tid][0] = p.ci0; s_box[tid][1] = p.ci1; s_box[tid][2] = p.inv2sig;
        s_ord[tid] = csr_order[b * NM + tid];
    }
    __syncthreads();

    const float fi = (float)i, fjb = (float)jb;
    int iu  = (i > 0) ? i - 1 : 0;
    int idn = (i < HH - 1) ? i + 1 : HH - 1;
    size_t base = ((size_t)b * NC + c0) * HW;

    const float4* pC = (const float4*)(hm + base + i   * WW + jb);
    const float4* pU = (const float4*)(hm + base + iu  * WW + jb);
    const float4* pD = (const float4*)(hm + base + idn * WW + jb);
    float* gp = out + OFF_GTHM + base + i * WW + jb;   // 4B-aligned only

    bool clampL = (lane31 == 0);
    bool clampR = (lane31 == 31);

    float bestv[4] = {-1.f, -1.f, -1.f, -1.f};
    int   bestc[4] = {0, 0, 0, 0};     // local class 0..9
    float facc = 0.0f;

    auto process = [&](float4 cC, float4 cU, float4 cD, int cc, float* gpc) {
        float h[4] = {cC.x, cC.y, cC.z, cC.w};
        float vm[4];
        vm[0] = fmax3(cU.x, h[0], cD.x);
        vm[1] = fmax3(cU.y, h[1], cD.y);
        vm[2] = fmax3(cU.z, h[2], cD.z);
        vm[3] = fmax3(cU.w, h[3], cD.w);
        float left  = __shfl_up(vm[3], 1);
        float right = __shfl_down(vm[0], 1);
        if (clampL) left  = vm[0];
        if (clampR) right = vm[3];
        float mx[4];
        mx[0] = fmax3(left,  vm[0], vm[1]);
        mx[1] = fmax3(vm[0], vm[1], vm[2]);
        mx[2] = fmax3(vm[1], vm[2], vm[3]);
        mx[3] = fmax3(vm[2], vm[3], right);
        #pragma unroll
        for (int k = 0; k < 4; ++k) {
            float p = (h[k] >= mx[k]) ? h[k] : 0.0f;
            if (p > bestv[k]) { bestv[k] = p; bestc[k] = cc; }
        }

        int c = c0 + cc;
        int s0 = s_start[c], s1 = s_start[c + 1];
        if (s0 == s1) {
            __builtin_nontemporal_store(0.0f, gpc + 0);
            __builtin_nontemporal_store(0.0f, gpc + 1);
            __builtin_nontemporal_store(0.0f, gpc + 2);
            __builtin_nontemporal_store(0.0f, gpc + 3);
            #pragma unroll
            for (int k = 0; k < 4; ++k)
                facc += h[k] * h[k] * __logf(1.0f - h[k]);
        } else {
            float gv[4] = {0.f, 0.f, 0.f, 0.f};
            for (int kk = s0; kk < s1; ++kk) {
                int m = s_ord[kk];
                float d0 = fi - s_box[m][0];
                float nis = -s_box[m][2];
                float dj = fjb - s_box[m][1];
                float e = d0 * d0;
                #pragma unroll
                for (int k = 0; k < 4; ++k) {
                    float d1 = dj + (float)k;
                    gv[k] = fmaxf(gv[k], __expf((e + d1 * d1) * nis));
                }
            }
            __builtin_nontemporal_store(gv[0], gpc + 0);
            __builtin_nontemporal_store(gv[1], gpc + 1);
            __builtin_nontemporal_store(gv[2], gpc + 2);
            __builtin_nontemporal_store(gv[3], gpc + 3);
            #pragma unroll
            for (int k = 0; k < 4; ++k) {
                float hk = h[k], ohk = 1.0f - hk;
                float gk = gv[k], omk = 1.0f - gk;
                float om2 = omk * omk, g2 = gk * gk;
                facc += (om2 * om2) * hk * hk * __logf(ohk)
                      + (g2 * g2) * ohk * ohk * __logf(hk);
            }
        }
    };

    float4 cC = *pC, cU = *pU, cD = *pD;
    for (int cc = 0; cc < NCL - 1; ++cc) {
        float4 nC = pC[HW4], nU = pU[HW4], nD = pD[HW4];   // prefetch next class
        process(cC, cU, cD, cc, gp);
        pC += HW4; pU += HW4; pD += HW4; gp += HW;
        cC = nC; cU = nU; cD = nD;
    }
    process(cC, cU, cD, NCL - 1, gp);

    // publish per-group results to LDS
    int pl = r * 128 + jb;           // 0..255, multiple of 4
    float4 bv4 = {bestv[0], bestv[1], bestv[2], bestv[3]};
    *(float4*)&s_val[wid][pl] = bv4;
    unsigned int cpk = (unsigned)bestc[0] | ((unsigned)bestc[1] << 8) |
                       ((unsigned)bestc[2] << 16) | ((unsigned)bestc[3] << 24);
    *(unsigned int*)&s_cls[wid][pl] = cpk;

    // focal wave reduction
    #pragma unroll
    for (int off = 32; off > 0; off >>= 1) facc += __shfl_down(facc, off);
    if (lane == 0) s_red[wid] = facc;
    __syncthreads();

    if (tid < 256) {
        float bv = -1.0f; int bi = 0;
        #pragma unroll
        for (int g2 = 0; g2 < NW; ++g2) {
            float v = s_val[g2][tid];
            if (v > bv) { bv = v; bi = g2 * NCL + (int)s_cls[g2][tid]; }  // strict >: first (smallest) class wins ties
        }
        int rr  = tid >> 7;          // 0/1
        int col = tid & 127;
        int ij  = (i0 + rr) * WW + col;
        int pix = b * HW + ij;
        out[OFF_VALUES + pix] = bv;
        out[OFF_IDXS + pix]   = (float)bi;
        out[OFF_KEEP + pix]   = (bv > 0.0f) ? 1.0f : 0.0f;

        const float* szb = sz  + (size_t)b * 2 * HW;
        const float* osb = osr + (size_t)b * 2 * HW;
        float s0v = szb[ij], s1v = szb[HW + ij];
        float o0 = osb[ij],  o1 = osb[HW + ij];
        float cx = (float)(i0 + rr) * 4.0f + o0;
        float cy = (float)col * 4.0f + o1;
        float4 bb;
        bb.x = fminf(fmaxf(cx - s0v * 0.5f, 0.0f), IMG);
        bb.y = fminf(fmaxf(cy - s1v * 0.5f, 0.0f), IMG);
        bb.z = fminf(fmaxf(cx + s0v * 0.5f, 0.0f), IMG);
        bb.w = fminf(fmaxf(cy + s1v * 0.5f, 0.0f), IMG);
        reinterpret_cast<float4*>(out + OFF_BBOX)[pix] = bb;
    }
    if (tid == 0) {
        float t = 0.0f;
        #pragma unroll
        for (int g2 = 0; g2 < NW; ++g2) t += s_red[g2];
        fpart[blk] = t;
    }
}

// ---------------- kernel 3: size/offset losses + focal partial reduction ----------------
__global__ void loss_kernel(const float* __restrict__ gtb, const float* __restrict__ sz,
                            const float* __restrict__ osr, const float* __restrict__ fpart,
                            float* __restrict__ out) {
    int t = threadIdx.x;
    int b = t >> 5, m = t & 31;
    __shared__ int s_ci[NB * NM];
    const float* g = gtb + t * 4;
    float x1 = g[0], y1 = g[1], x2 = g[2], y2 = g[3];
    float cx = (x1 + x2) * 0.5f, cy = (y1 + y2) * 0.5f;
    float c0f = floorf(cx * 0.25f), c1f = floorf(cy * 0.25f);
    int ci0 = (int)c0f, ci1 = (int)c1f;
    s_ci[t] = ci0 * WW + ci1;
    __syncthreads();

    bool winner = true;
    int mycell = s_ci[t];
    for (int m2 = m + 1; m2 < NM; ++m2)
        if (s_ci[b * NM + m2] == mycell) { winner = false; break; }

    float nloc = 0.0f, szs = 0.0f, oss = 0.0f;
    if (winner) {
        nloc = 1.0f;
        float w = x2 - x1, h = y2 - y1;
        float offx = cx * 0.25f - c0f, offy = cy * 0.25f - c1f;
        size_t pb = (size_t)b * 2 * HW + (size_t)ci0 * WW + ci1;
        float ps0 = sz[pb], ps1 = sz[pb + HW];
        float po0 = osr[pb], po1 = osr[pb + HW];
        szs = smooth_l1(ps0, w) + smooth_l1(ps1, h);
        oss = smooth_l1(po0, offx) + smooth_l1(po1, offy);
    }

    // focal partials: 1024 entries, 2 per thread
    float fsum = fpart[t] + fpart[t + 512];

    #pragma unroll
    for (int off = 32; off > 0; off >>= 1) {
        nloc += __shfl_down(nloc, off);
        szs  += __shfl_down(szs, off);
        oss  += __shfl_down(oss, off);
        fsum += __shfl_down(fsum, off);
    }
    __shared__ float red[8][4];
    int wid = t >> 6;
    if ((t & 63) == 0) { red[wid][0] = nloc; red[wid][1] = szs; red[wid][2] = oss; red[wid][3] = fsum; }
    __syncthreads();
    if (t == 0) {
        float n = 0.0f, ss = 0.0f, os_ = 0.0f, ft = 0.0f;
        for (int w2 = 0; w2 < 8; ++w2) { n += red[w2][0]; ss += red[w2][1]; os_ += red[w2][2]; ft += red[w2][3]; }
        out[OFF_SZL] = ss / (2.0f * n) / n;
        out[OFF_OSL] = os_ / (2.0f * n) / n;
        out[OFF_PFL] = -ft;
    }
}

extern "C" void kernel_launch(void* const* d_in, const int* in_sizes, int n_in,
                              void* d_out, int out_size, void* d_ws, size_t ws_size,
                              hipStream_t stream) {
    const float* hm  = (const float*)d_in[0];
    const float* sz  = (const float*)d_in[1];
    const float* osr = (const float*)d_in[2];
    const float* gtb = (const float*)d_in[3];
    const int*   gtc = (const int*)d_in[4];
    float* out = (float*)d_out;

    BoxParam* bp   = (BoxParam*)((char*)d_ws + WS_BP);
    int* csr_start = (int*)((char*)d_ws + WS_CSRS);
    int* csr_order = (int*)((char*)d_ws + WS_CSRO);
    float* fpart   = (float*)((char*)d_ws + WS_FPART);

    setup_kernel<<<1, 512, 0, stream>>>(gtb, gtc, bp, csr_start, csr_order);
    main_kernel<<<MAIN_BLOCKS, 512, 0, stream>>>(hm, sz, osr, bp, csr_start, csr_order, fpart, out);
    loss_kernel<<<1, 512, 0, stream>>>(gtb, sz, osr, fpart, out);
}